// Round 4
// baseline (215.112 us; speedup 1.0000x reference)
//
#include <hip/hip_runtime.h>

// SpectralConv2dRealFreq: B=16, Cin=Cout=64, H=W=128, modes=33 (k in [-16,16])
// out = Re( iDFT2_trunc( (DFT2_trunc(x)) * (wr + i*wi) ) ), separable 1/sqrt(N) DFTs.
//
// Round 4: MFMA everywhere.
//   fwd:  G = Fh · x · Fw^T per image (bf16 MFMA), X2[img][mode-linear] float2
//   mix:  per-mode complex GEMM K[b,o] = sum_c X[b,c] R[c,o] via MFMA (M=16=all b).
//         16-consecutive-mode blocks consume weight cachelines fully (read once).
//         Compact output Kbf[img][ri][mode] bf16 (no U duplication, no padU).
//   inv:  2-GEMM complex form: T1 = Kr·Cw − Ki·Sw, T2 = Ki·Cw + Kr·Sw,
//         out = Ch^T·T1 − Sh^T·T2 (stacked 96-row middle, XOR-swizzled LDS).

#define NB   16
#define NC   64
#define NO   64
#define NH   128
#define NW   128
#define NM   33
#define WMODE (NM*NM)    // 1089 (linear mode count, also weight mode stride)
#define MPAD  1104       // Kbf mode stride (69*16)
#define NIMG 1024

typedef __attribute__((ext_vector_type(8))) short s8v;   // 8 bf16 (4 VGPRs)
typedef __attribute__((ext_vector_type(4))) float f4v;   // MFMA accumulator

__device__ inline unsigned short f2bf(float f) {
  union { float f; unsigned u; } v; v.f = f;
  unsigned r = (v.u + 0x7FFFu + ((v.u >> 16) & 1u)) >> 16;   // RNE
  return (unsigned short)r;
}

__device__ inline s8v pack8(float4 a, float4 b) {
  s8v r;
  r[0] = (short)f2bf(a.x); r[1] = (short)f2bf(a.y);
  r[2] = (short)f2bf(a.z); r[3] = (short)f2bf(a.w);
  r[4] = (short)f2bf(b.x); r[5] = (short)f2bf(b.y);
  r[6] = (short)f2bf(b.z); r[7] = (short)f2bf(b.w);
  return r;
}

__device__ inline uint2 pack4(f4v a) {
  uint2 p;
  p.x = (unsigned)f2bf(a[0]) | ((unsigned)f2bf(a[1]) << 16);
  p.y = (unsigned)f2bf(a[2]) | ((unsigned)f2bf(a[3]) << 16);
  return p;
}

// stacked-phase value: f in [0,33): cos row f; [33,66): sin row f-33; >=66: 0
__device__ inline unsigned short phase_bf(int f, int x) {
  if (f >= 66) return 0;
  int g = (f < 33) ? f : f - 33;
  int fr = (g <= 16) ? g : g + 95;          // signed freq mod 128
  int ph = (fr * x) & 127;                  // exact integer phase
  float ang = (float)ph * 0.04908738521234052f;   // 2*pi/128
  float v = ((f < 33) ? cosf(ang) : sinf(ang)) * 0.08838834764831845f;  // /sqrt(128)
  return f2bf(v);
}

// --------------------------------------------------- fragment-layout tables
// T1 fwd-B : [ks<4][jt<5][l][e] = P(f=jt*16+lr,        x=ks*32+lg*8+e)
// T2 fwd-A : [it<5][ks<4][l][e] = P(f=it*16+lr,        x=ks*32+lg*8+e)
// T3 inv-B1: [cs<2][ks<2][mt<8][l][e] = P(f=cs*33+j (j<33 else 0), x=mt*16+lr), j=ks*32+lg*8+e
// T4 inv-A2: [nt<8][ks<3][l][e] = P(f: i'<48 -> cos i' ; else sin i'-48, x=nt*16+lr), i'=ks*32+lg*8+e
__global__ __launch_bounds__(256) void spc_tables(short* __restrict__ T1,
                                                  short* __restrict__ T2,
                                                  short* __restrict__ T3,
                                                  short* __restrict__ T4) {
  int tid = blockIdx.x * 256 + threadIdx.x;
  if (tid >= 49152) return;
  int f, x; short* dst;
  if (tid < 10240) {
    int e = tid & 7, l = (tid >> 3) & 63, q = tid >> 9;     // q = ks*5+jt
    int ks = q / 5, jt = q - 5 * ks;
    f = jt * 16 + (l & 15); x = ks * 32 + (l >> 4) * 8 + e; dst = T1 + tid;
  } else if (tid < 20480) {
    int u = tid - 10240;
    int e = u & 7, l = (u >> 3) & 63, q = u >> 9;           // q = it*4+ks
    int it = q >> 2, ks = q & 3;
    f = it * 16 + (l & 15); x = ks * 32 + (l >> 4) * 8 + e; dst = T2 + u;
  } else if (tid < 36864) {
    int u = tid - 20480;
    int e = u & 7, l = (u >> 3) & 63, q = u >> 9;           // q = (cs*2+ks)*8+mt
    int cs = q >> 4, ks = (q >> 3) & 1, mt = q & 7;
    int j = ks * 32 + (l >> 4) * 8 + e;
    f = (j < 33) ? cs * 33 + j : 66;
    x = mt * 16 + (l & 15); dst = T3 + u;
  } else {
    int u = tid - 36864;
    int e = u & 7, l = (u >> 3) & 63, q = u >> 9;           // q = nt*3+ks
    int nt = q / 3, ks = q - 3 * nt;
    int i2 = ks * 32 + (l >> 4) * 8 + e;
    if (i2 < 48) f = (i2 < 33) ? i2 : 66;
    else         f = (i2 - 48 < 33) ? 33 + (i2 - 48) : 66;
    x = nt * 16 + (l & 15); dst = T4 + u;
  }
  *dst = (short)phase_bf(f, x);
}

// --------------------------------------------------------------- forward DFT
__global__ __launch_bounds__(256) void spc_fwd_mfma(const float* __restrict__ x,
                                                    const s8v* __restrict__ T1,
                                                    const s8v* __restrict__ T2,
                                                    float2* __restrict__ X2) {
  __shared__ short Wt[80 * 128];   // W1T[j][n] bf16, granule-4 XOR swizzle
  __shared__ float Gs[80 * 84];    // G f32, stride 84
  const int t = threadIdx.x;
  const int l = t & 63;
  const int w = t >> 6;
  const int lr = l & 15;
  const int lg = l >> 4;
  const int img = blockIdx.x;
  const float* xp = x + (size_t)img * (NH * NW);

  // stage 1: W1[n][j] = sum_m x[n][m] * Fw[j][m]; tiles (nt=2w..2w+1, jt 0..4)
  for (int nn = 0; nn < 2; ++nn) {
    const int nt = 2 * w + nn;
    const float* xrow = xp + (nt * 16 + lr) * NW + lg * 8;
    s8v a[4];
#pragma unroll
    for (int ks = 0; ks < 4; ++ks) {
      float4 f0 = *reinterpret_cast<const float4*>(xrow + ks * 32);
      float4 f1 = *reinterpret_cast<const float4*>(xrow + ks * 32 + 4);
      a[ks] = pack8(f0, f1);
    }
#pragma unroll
    for (int jt = 0; jt < 5; ++jt) {
      f4v acc = {0.f, 0.f, 0.f, 0.f};
#pragma unroll
      for (int ks = 0; ks < 4; ++ks) {
        s8v b = T1[(ks * 5 + jt) * 64 + l];
        acc = __builtin_amdgcn_mfma_f32_16x16x32_bf16(a[ks], b, acc, 0, 0, 0);
      }
      int j = jt * 16 + lr;
      int g = ((nt * 16 + lg * 4) >> 2) ^ ((j & 7) << 2);
      *reinterpret_cast<uint2*>(&Wt[j * 128 + g * 4]) = pack4(acc);
    }
  }
  __syncthreads();

  // stage 2: G[i][j] = sum_n Fh[i][n] * W1[n][j]; 25 tiles round-robin
  for (int tix = w; tix < 25; tix += 4) {
    int it = tix / 5, j2 = tix - 5 * it;
    int jrow = j2 * 16 + lr;
    f4v acc = {0.f, 0.f, 0.f, 0.f};
#pragma unroll
    for (int ks = 0; ks < 4; ++ks) {
      s8v afr = T2[(it * 4 + ks) * 64 + l];
      int g = (ks * 8 + lg * 2) ^ ((jrow & 7) << 2);
      s8v b = *reinterpret_cast<const s8v*>(&Wt[jrow * 128 + g * 4]);
      acc = __builtin_amdgcn_mfma_f32_16x16x32_bf16(afr, b, acc, 0, 0, 0);
    }
    int gi = it * 16 + lg * 4;
#pragma unroll
    for (int r = 0; r < 4; ++r) Gs[(gi + r) * 84 + jrow] = acc[r];
  }
  __syncthreads();

  // epilogue: X2r = G11 - G22, X2i = -(G12 + G21); linear mode layout
  float2* X2p = X2 + (size_t)img * WMODE;
  for (int idx = t; idx < WMODE; idx += 256) {
    int i = idx / 33, j = idx - 33 * i;
    float g11 = Gs[i * 84 + j];
    float g22 = Gs[(i + 33) * 84 + (j + 33)];
    float g12 = Gs[i * 84 + (j + 33)];
    float g21 = Gs[(i + 33) * 84 + j];
    X2p[idx] = make_float2(g11 - g22, -(g12 + g21));
  }
}

// ---------------------------------------------------------------- channel mix
// K[b,o,mode] = sum_c X[b,c,mode] * (wr + i wi)[c,o,mode]; MFMA M=16(b) N=16(o) K=64(c)
__global__ __launch_bounds__(128) void spc_mix_mfma(const float* __restrict__ wr,
                                                    const float* __restrict__ wi,
                                                    const float2* __restrict__ X2,
                                                    short* __restrict__ Kbf) {
  __shared__ short Kls[8 * 2 * 16 * 16];   // [mm][ri][o_l][b] bf16, 8 KB
  const int t = threadIdx.x;
  const int l = t & 63;
  const int w = t >> 6;        // wave 0..1
  const int lr = l & 15;
  const int lg = l >> 4;
  const int ot = blockIdx.x;               // o-tile 0..3
  const int m0 = blockIdx.y * 16 + blockIdx.z * 8;   // mode base (8 per block)
  const int o = ot * 16 + lr;

#pragma unroll
  for (int mi = 0; mi < 4; ++mi) {
    const int mm = w * 4 + mi;
    int mL = m0 + mm; if (mL > 1088) mL = 1088;      // clamp pad modes
    // A gather: Xr/Xi fragments (row b=lr, k c=ks*32+lg*8+e)
    s8v xr[2], xi[2];
#pragma unroll
    for (int ks = 0; ks < 2; ++ks) {
#pragma unroll
      for (int e = 0; e < 8; ++e) {
        float2 v = X2[(size_t)(lr * 64 + ks * 32 + lg * 8 + e) * WMODE + mL];
        xr[ks][e] = (short)f2bf(v.x);
        xi[ks][e] = (short)f2bf(v.y);
      }
    }
    // B gather: Rr/Ri fragments (k c, col o=lr)
    s8v rr[2], ri[2], nri[2];
#pragma unroll
    for (int ks = 0; ks < 2; ++ks) {
#pragma unroll
      for (int e = 0; e < 8; ++e) {
        size_t widx = (size_t)((ks * 32 + lg * 8 + e) * 64 + o) * WMODE + mL;
        rr[ks][e] = (short)f2bf(wr[widx]);
        unsigned short riv = f2bf(wi[widx]);
        ri[ks][e] = (short)riv;
        nri[ks][e] = (short)(riv ^ 0x8000u);
      }
    }
    f4v kr = {0.f, 0.f, 0.f, 0.f}, ki = {0.f, 0.f, 0.f, 0.f};
#pragma unroll
    for (int ks = 0; ks < 2; ++ks) {
      kr = __builtin_amdgcn_mfma_f32_16x16x32_bf16(xr[ks], rr[ks], kr, 0, 0, 0);
      ki = __builtin_amdgcn_mfma_f32_16x16x32_bf16(xr[ks], ri[ks], ki, 0, 0, 0);
      kr = __builtin_amdgcn_mfma_f32_16x16x32_bf16(xi[ks], nri[ks], kr, 0, 0, 0);
      ki = __builtin_amdgcn_mfma_f32_16x16x32_bf16(xi[ks], rr[ks], ki, 0, 0, 0);
    }
    // D: col=o_l=lr, rows b=lg*4+r  ->  Kls[mm][ri][lr][lg*4..+3]
    *reinterpret_cast<uint2*>(&Kls[((mm * 2 + 0) * 16 + lr) * 16 + lg * 4]) = pack4(kr);
    *reinterpret_cast<uint2*>(&Kls[((mm * 2 + 1) * 16 + lr) * 16 + lg * 4]) = pack4(ki);
  }
  __syncthreads();

  // write-out: Kbf[img][ri][m0..m0+7], 16-B aligned stores
#pragma unroll
  for (int rep = 0; rep < 2; ++rep) {
    int ti = t + rep * 128;
    int b = ti >> 4, ol = ti & 15;
    size_t img = (size_t)b * 64 + ot * 16 + ol;
#pragma unroll
    for (int ri2 = 0; ri2 < 2; ++ri2) {
      unsigned short tmp[8];
#pragma unroll
      for (int mm = 0; mm < 8; ++mm) {
        int mL = m0 + mm;
        tmp[mm] = (mL <= 1088) ? (unsigned short)Kls[((mm * 2 + ri2) * 16 + ol) * 16 + b] : 0;
      }
      uint4 u;
      u.x = (unsigned)tmp[0] | ((unsigned)tmp[1] << 16);
      u.y = (unsigned)tmp[2] | ((unsigned)tmp[3] << 16);
      u.z = (unsigned)tmp[4] | ((unsigned)tmp[5] << 16);
      u.w = (unsigned)tmp[6] | ((unsigned)tmp[7] << 16);
      *reinterpret_cast<uint4*>(Kbf + img * (2 * MPAD) + ri2 * MPAD + m0) = u;
    }
  }
}

// ---------------------------------------------------------------- inverse DFT
__global__ __launch_bounds__(256) void spc_inv_mfma(const short* __restrict__ Kbf,
                                                    const s8v* __restrict__ T3,
                                                    const s8v* __restrict__ T4,
                                                    float* __restrict__ out) {
  __shared__ short Kls2[2 * MPAD];  // per-image K slice (4416 B)
  __shared__ short Vt[128 * 128];   // stacked [T1; -T2] rows i'<96, [m][i'] swizzled
  const int t = threadIdx.x;
  const int l = t & 63;
  const int w = t >> 6;
  const int lr = l & 15;
  const int lg = l >> 4;
  const int img = blockIdx.x;

  {
    const uint4* src = reinterpret_cast<const uint4*>(Kbf + (size_t)img * (2 * MPAD));
    uint4* dstl = reinterpret_cast<uint4*>(Kls2);
    for (int idx = t; idx < 276; idx += 256) dstl[idx] = src[idx];
  }
  __syncthreads();

  // build Kr/Ki A-fragments: [ri][it<3][ks<2], row i=it*16+lr, k j=ks*32+lg*8+e
  s8v fr[2][3][2];
#pragma unroll
  for (int ri2 = 0; ri2 < 2; ++ri2)
#pragma unroll
    for (int it = 0; it < 3; ++it)
#pragma unroll
      for (int ks = 0; ks < 2; ++ks) {
        const int i = it * 16 + lr;
#pragma unroll
        for (int e = 0; e < 8; ++e) {
          const int j = ks * 32 + lg * 8 + e;
          unsigned short v = (i < 33 && j < 33)
              ? (unsigned short)Kls2[ri2 * MPAD + i * 33 + j] : (unsigned short)0;
          fr[ri2][it][ks][e] = (short)v;
        }
      }

  // stage 1: T1[i][m] = Kr·Cw − Ki·Sw ; T2 = Ki·Cw + Kr·Sw ; store [T1; −T2]
  for (int mm = 0; mm < 2; ++mm) {
    const int mt = w * 2 + mm;
    const int m = mt * 16 + lr;
    s8v cw[2], sw[2], nsw[2];
#pragma unroll
    for (int ks = 0; ks < 2; ++ks) {
      cw[ks] = T3[((0 * 2 + ks) * 8 + mt) * 64 + l];
      sw[ks] = T3[((1 * 2 + ks) * 8 + mt) * 64 + l];
#pragma unroll
      for (int e = 0; e < 8; ++e)
        nsw[ks][e] = (short)(((unsigned short)sw[ks][e]) ^ 0x8000u);
    }
#pragma unroll
    for (int it = 0; it < 3; ++it) {
      f4v t1 = {0.f, 0.f, 0.f, 0.f}, t2 = {0.f, 0.f, 0.f, 0.f};
#pragma unroll
      for (int ks = 0; ks < 2; ++ks) {
        t1 = __builtin_amdgcn_mfma_f32_16x16x32_bf16(fr[0][it][ks], cw[ks],  t1, 0, 0, 0);
        t1 = __builtin_amdgcn_mfma_f32_16x16x32_bf16(fr[1][it][ks], nsw[ks], t1, 0, 0, 0);
        t2 = __builtin_amdgcn_mfma_f32_16x16x32_bf16(fr[1][it][ks], cw[ks],  t2, 0, 0, 0);
        t2 = __builtin_amdgcn_mfma_f32_16x16x32_bf16(fr[0][it][ks], sw[ks],  t2, 0, 0, 0);
      }
      const int base1 = it * 16 + lg * 4;
      const int g1 = (base1 >> 2) ^ ((m & 7) << 2);
      *reinterpret_cast<uint2*>(&Vt[m * 128 + g1 * 4]) = pack4(t1);
      f4v nt2v = {-t2[0], -t2[1], -t2[2], -t2[3]};
      const int g2 = ((48 + base1) >> 2) ^ ((m & 7) << 2);
      *reinterpret_cast<uint2*>(&Vt[m * 128 + g2 * 4]) = pack4(nt2v);
    }
  }
  __syncthreads();

  // stage 2: out[n][m] = sum_{i'<96} A2[n][i'] · Vt[i'][m]
  float* op = out + (size_t)img * (NH * NW);
  for (int nn = 0; nn < 2; ++nn) {
    const int nt = w * 2 + nn;
    s8v a[3];
#pragma unroll
    for (int ks = 0; ks < 3; ++ks) a[ks] = T4[(nt * 3 + ks) * 64 + l];
    for (int mt = 0; mt < 8; ++mt) {
      const int m = mt * 16 + lr;
      f4v acc = {0.f, 0.f, 0.f, 0.f};
#pragma unroll
      for (int ks = 0; ks < 3; ++ks) {
        const int g = (ks * 8 + lg * 2) ^ ((m & 7) << 2);
        s8v bb = *reinterpret_cast<const s8v*>(&Vt[m * 128 + g * 4]);
        acc = __builtin_amdgcn_mfma_f32_16x16x32_bf16(a[ks], bb, acc, 0, 0, 0);
      }
      const int n = nt * 16 + lg * 4;
#pragma unroll
      for (int r = 0; r < 4; ++r) op[(n + r) * NW + m] = acc[r];
    }
  }
}

// ---------------------------------------------------------------- launch
extern "C" void kernel_launch(void* const* d_in, const int* in_sizes, int n_in,
                              void* d_out, int out_size, void* d_ws, size_t ws_size,
                              hipStream_t stream) {
  const float* x  = (const float*)d_in[0];
  const float* wr = (const float*)d_in[1];
  const float* wi = (const float*)d_in[2];
  float* out = (float*)d_out;

  char* ws = (char*)d_ws;
  short* T1 = (short*)(ws);                         // 20480 B
  short* T2 = (short*)(ws + 20480);                 // 20480 B
  short* T3 = (short*)(ws + 40960);                 // 32768 B
  short* T4 = (short*)(ws + 73728);                 // 24576 B
  float2* X2 = (float2*)(ws + 98304);               // 1024*1089*8 = 8,921,088 B
  short* Kbf = (short*)(ws + 98304 + 8921088);      // 1024*2*1104*2 = 4,521,984 B
  // total ~13.5 MB

  hipLaunchKernelGGL(spc_tables, dim3(192), dim3(256), 0, stream, T1, T2, T3, T4);
  hipLaunchKernelGGL(spc_fwd_mfma, dim3(NIMG), dim3(256), 0, stream,
                     x, (const s8v*)T1, (const s8v*)T2, X2);
  hipLaunchKernelGGL(spc_mix_mfma, dim3(4, 69, 2), dim3(128), 0, stream,
                     wr, wi, X2, Kbf);
  hipLaunchKernelGGL(spc_inv_mfma, dim3(NIMG), dim3(256), 0, stream,
                     Kbf, (const s8v*)T3, (const s8v*)T4, out);
}

// Round 5
// 81.202 us; speedup vs baseline: 2.6491x; 2.6491x over previous
//
#include <hip/hip_runtime.h>

// SpectralConv2dRealFreq: B=16, Cin=Cout=64, H=W=128, modes=33 (k in [-16,16])
// out = Re( iDFT2_trunc( (DFT2_trunc(x)) * (wr + i*wi) ) ), separable 1/sqrt(N) DFTs.
//
// Round 5: fix the mix over-fetch with repack passes; all GEMMs MFMA.
//   wrepack: wr/wi fp32 [c][o][m] -> Wfrag bf16 fragment layout (read-once in mix)
//   fwd:     G = Fh · x · Fw^T per image; X2 packed bf16 (re|im) [img][m]
//   xrepack: X2 [b][c][m] -> Xp [m][c][b] (LDS transpose, coalesced both sides)
//   mix:     per-mode complex GEMM K[b,o] = sum_c X[b,c] R[c,o]; wave=mode;
//            Kbf [mg][img][ri][mm4] bf16, full-line writes
//   inv:     2-GEMM complex form, out = Ch^T·T1 − Sh^T·T2 (as round 4)

#define NB   16
#define NC   64
#define NO   64
#define NH   128
#define NW   128
#define NM   33
#define WMODE (NM*NM)    // 1089 linear modes
#define MPAD  1104       // Kls2 mode stride in inv (>= 273*4)
#define NIMG 1024

typedef __attribute__((ext_vector_type(8))) short s8v;   // 8 bf16 (4 VGPRs)
typedef __attribute__((ext_vector_type(4))) float f4v;   // MFMA accumulator

__device__ inline unsigned short f2bf(float f) {
  union { float f; unsigned u; } v; v.f = f;
  unsigned r = (v.u + 0x7FFFu + ((v.u >> 16) & 1u)) >> 16;   // RNE
  return (unsigned short)r;
}

__device__ inline s8v pack8(float4 a, float4 b) {
  s8v r;
  r[0] = (short)f2bf(a.x); r[1] = (short)f2bf(a.y);
  r[2] = (short)f2bf(a.z); r[3] = (short)f2bf(a.w);
  r[4] = (short)f2bf(b.x); r[5] = (short)f2bf(b.y);
  r[6] = (short)f2bf(b.z); r[7] = (short)f2bf(b.w);
  return r;
}

__device__ inline uint2 pack4(f4v a) {
  uint2 p;
  p.x = (unsigned)f2bf(a[0]) | ((unsigned)f2bf(a[1]) << 16);
  p.y = (unsigned)f2bf(a[2]) | ((unsigned)f2bf(a[3]) << 16);
  return p;
}

// stacked-phase value: f in [0,33): cos row f; [33,66): sin row f-33; >=66: 0
__device__ inline unsigned short phase_bf(int f, int x) {
  if (f >= 66) return 0;
  int g = (f < 33) ? f : f - 33;
  int fr = (g <= 16) ? g : g + 95;          // signed freq mod 128
  int ph = (fr * x) & 127;                  // exact integer phase
  float ang = (float)ph * 0.04908738521234052f;   // 2*pi/128
  float v = ((f < 33) ? cosf(ang) : sinf(ang)) * 0.08838834764831845f;  // /sqrt(128)
  return f2bf(v);
}

// --------------------------------------------------- fragment-layout tables
// T1 fwd-B : [ks<4][jt<5][l][e] = P(f=jt*16+lr,        x=ks*32+lg*8+e)
// T2 fwd-A : [it<5][ks<4][l][e] = P(f=it*16+lr,        x=ks*32+lg*8+e)
// T3 inv-B1: [cs<2][ks<2][mt<8][l][e] = P(f=cs*33+j (j<33 else 0), x=mt*16+lr), j=ks*32+lg*8+e
// T4 inv-A2: [nt<8][ks<3][l][e] = P(f: i'<48 -> cos i' ; else sin i'-48, x=nt*16+lr), i'=ks*32+lg*8+e
__global__ __launch_bounds__(256) void spc_tables(short* __restrict__ T1,
                                                  short* __restrict__ T2,
                                                  short* __restrict__ T3,
                                                  short* __restrict__ T4) {
  int tid = blockIdx.x * 256 + threadIdx.x;
  if (tid >= 49152) return;
  int f, x; short* dst;
  if (tid < 10240) {
    int e = tid & 7, l = (tid >> 3) & 63, q = tid >> 9;     // q = ks*5+jt
    int ks = q / 5, jt = q - 5 * ks;
    f = jt * 16 + (l & 15); x = ks * 32 + (l >> 4) * 8 + e; dst = T1 + tid;
  } else if (tid < 20480) {
    int u = tid - 10240;
    int e = u & 7, l = (u >> 3) & 63, q = u >> 9;           // q = it*4+ks
    int it = q >> 2, ks = q & 3;
    f = it * 16 + (l & 15); x = ks * 32 + (l >> 4) * 8 + e; dst = T2 + u;
  } else if (tid < 36864) {
    int u = tid - 20480;
    int e = u & 7, l = (u >> 3) & 63, q = u >> 9;           // q = (cs*2+ks)*8+mt
    int cs = q >> 4, ks = (q >> 3) & 1, mt = q & 7;
    int j = ks * 32 + (l >> 4) * 8 + e;
    f = (j < 33) ? cs * 33 + j : 66;
    x = mt * 16 + (l & 15); dst = T3 + u;
  } else {
    int u = tid - 36864;
    int e = u & 7, l = (u >> 3) & 63, q = u >> 9;           // q = nt*3+ks
    int nt = q / 3, ks = q - 3 * nt;
    int i2 = ks * 32 + (l >> 4) * 8 + e;
    if (i2 < 48) f = (i2 < 33) ? i2 : 66;
    else         f = (i2 - 48 < 33) ? 33 + (i2 - 48) : 66;
    x = nt * 16 + (l & 15); dst = T4 + u;
  }
  *dst = (short)phase_bf(f, x);
}

// ------------------------------------------------------------ weight repack
// Wfrag[(((m*4+ot)*2+pl)*2+ks)*512 + l*8 + e] = bf16(w_pl[c][o][m]),
//   c = ks*32 + (l>>4)*8 + e, o = ot*16 + (l&15).  m padded to 1104 (clamped).
__global__ __launch_bounds__(256) void spc_wrepack(const float* __restrict__ wr,
                                                   const float* __restrict__ wi,
                                                   short* __restrict__ Wfrag) {
  __shared__ unsigned short Ls[64 * 16 * 17];   // [c][o][m(17 pad)]
  const int t = threadIdx.x;
  const int ot = blockIdx.x;       // 0..3
  const int mg = blockIdx.y;       // 0..68
  const int m0 = mg * 16;
  const int oo = t >> 4, mm = t & 15;
  int msrc = m0 + mm; if (msrc > 1088) msrc = 1088;

  for (int pl = 0; pl < 2; ++pl) {
    const float* src = pl ? wi : wr;
    __syncthreads();
    for (int c = 0; c < 64; ++c) {
      float v = src[(size_t)(c * 64 + ot * 16 + oo) * WMODE + msrc];
      Ls[(c * 16 + oo) * 17 + mm] = f2bf(v);
    }
    __syncthreads();
    for (int pass = 0; pass < 8; ++pass) {
      int p = pass * 4 + (t >> 6);           // 0..31 = m_l*2 + ks
      int m_l = p >> 1, ks = p & 1;
      int l = t & 63;
      int lr = l & 15, lg = l >> 4;
      unsigned short v[8];
#pragma unroll
      for (int e = 0; e < 8; ++e)
        v[e] = Ls[((ks * 32 + lg * 8 + e) * 16 + lr) * 17 + m_l];
      uint4 u;
      u.x = (unsigned)v[0] | ((unsigned)v[1] << 16);
      u.y = (unsigned)v[2] | ((unsigned)v[3] << 16);
      u.z = (unsigned)v[4] | ((unsigned)v[5] << 16);
      u.w = (unsigned)v[6] | ((unsigned)v[7] << 16);
      size_t frag = (((size_t)(m0 + m_l) * 4 + ot) * 2 + pl) * 2 + ks;
      *reinterpret_cast<uint4*>(Wfrag + frag * 512 + l * 8) = u;
    }
  }
}

// --------------------------------------------------------------- forward DFT
__global__ __launch_bounds__(256) void spc_fwd_mfma(const float* __restrict__ x,
                                                    const s8v* __restrict__ T1,
                                                    const s8v* __restrict__ T2,
                                                    unsigned* __restrict__ X2u) {
  __shared__ short Wt[80 * 128];   // W1T[j][n] bf16, granule-4 XOR swizzle
  __shared__ float Gs[80 * 84];    // G f32, stride 84
  const int t = threadIdx.x;
  const int l = t & 63;
  const int w = t >> 6;
  const int lr = l & 15;
  const int lg = l >> 4;
  const int img = blockIdx.x;
  const float* xp = x + (size_t)img * (NH * NW);

  // stage 1: W1[n][j] = sum_m x[n][m] * Fw[j][m]; tiles (nt=2w..2w+1, jt 0..4)
  for (int nn = 0; nn < 2; ++nn) {
    const int nt = 2 * w + nn;
    const float* xrow = xp + (nt * 16 + lr) * NW + lg * 8;
    s8v a[4];
#pragma unroll
    for (int ks = 0; ks < 4; ++ks) {
      float4 f0 = *reinterpret_cast<const float4*>(xrow + ks * 32);
      float4 f1 = *reinterpret_cast<const float4*>(xrow + ks * 32 + 4);
      a[ks] = pack8(f0, f1);
    }
#pragma unroll
    for (int jt = 0; jt < 5; ++jt) {
      f4v acc = {0.f, 0.f, 0.f, 0.f};
#pragma unroll
      for (int ks = 0; ks < 4; ++ks) {
        s8v b = T1[(ks * 5 + jt) * 64 + l];
        acc = __builtin_amdgcn_mfma_f32_16x16x32_bf16(a[ks], b, acc, 0, 0, 0);
      }
      int j = jt * 16 + lr;
      int g = ((nt * 16 + lg * 4) >> 2) ^ ((j & 7) << 2);
      *reinterpret_cast<uint2*>(&Wt[j * 128 + g * 4]) = pack4(acc);
    }
  }
  __syncthreads();

  // stage 2: G[i][j] = sum_n Fh[i][n] * W1[n][j]; 25 tiles round-robin
  for (int tix = w; tix < 25; tix += 4) {
    int it = tix / 5, j2 = tix - 5 * it;
    int jrow = j2 * 16 + lr;
    f4v acc = {0.f, 0.f, 0.f, 0.f};
#pragma unroll
    for (int ks = 0; ks < 4; ++ks) {
      s8v afr = T2[(it * 4 + ks) * 64 + l];
      int g = (ks * 8 + lg * 2) ^ ((jrow & 7) << 2);
      s8v b = *reinterpret_cast<const s8v*>(&Wt[jrow * 128 + g * 4]);
      acc = __builtin_amdgcn_mfma_f32_16x16x32_bf16(afr, b, acc, 0, 0, 0);
    }
    int gi = it * 16 + lg * 4;
#pragma unroll
    for (int r = 0; r < 4; ++r) Gs[(gi + r) * 84 + jrow] = acc[r];
  }
  __syncthreads();

  // epilogue: X2r = G11 - G22, X2i = -(G12 + G21); packed bf16 pair per mode
  unsigned* X2p = X2u + (size_t)img * WMODE;
  for (int idx = t; idx < WMODE; idx += 256) {
    int i = idx / 33, j = idx - 33 * i;
    float g11 = Gs[i * 84 + j];
    float g22 = Gs[(i + 33) * 84 + (j + 33)];
    float g12 = Gs[i * 84 + (j + 33)];
    float g21 = Gs[(i + 33) * 84 + j];
    X2p[idx] = (unsigned)f2bf(g11 - g22) | ((unsigned)f2bf(-(g12 + g21)) << 16);
  }
}

// ------------------------------------------------------------------ X repack
// Xp[(m*64 + c)*16 + b] = X2u[(b*64 + c)*WMODE + m]
__global__ __launch_bounds__(256) void spc_xrepack(const unsigned* __restrict__ X2u,
                                                   unsigned* __restrict__ Xp) {
  __shared__ unsigned Ls[64 * 65];   // [row=cl*16+b][m_l], pad 65
  const int t = threadIdx.x;
  const int l = t & 63;
  const int w = t >> 6;
  const int m0 = blockIdx.x * 64;    // 18 chunks (last partial)
  const int c0 = blockIdx.y * 4;     // 16 chunks

  for (int rr = 0; rr < 16; ++rr) {
    int r = w * 16 + rr;             // row = cl*16 + b, with cl=r>>4, b=r&15
    int b = r & 15, cl = r >> 4;
    int m = m0 + l;
    unsigned v = 0;
    if (m < WMODE) v = X2u[(size_t)(b * 64 + c0 + cl) * WMODE + m];
    Ls[r * 65 + l] = v;
  }
  __syncthreads();
  for (int p = 0; p < 16; ++p) {
    int m_l = p * 4 + w;
    int m = m0 + m_l;
    if (m >= WMODE) continue;
    int cl = l >> 4, b = l & 15;
    unsigned v = Ls[(cl * 16 + b) * 65 + m_l];
    Xp[((size_t)m * 64 + c0 + cl) * 16 + b] = v;
  }
}

// ---------------------------------------------------------------- channel mix
// wave = one mode; K[b,o] = sum_c X[b,c]·R[c,o] (complex), M=16(b) N=16(o) K=64(c)
// Kbf[((mg*1024+img)*2+ri)*4 + mm] bf16, mg = mode group of 4
__global__ __launch_bounds__(256) void spc_mix_mfma(const unsigned* __restrict__ Xp,
                                                    const s8v* __restrict__ Wfrag,
                                                    short* __restrict__ Kbf) {
  __shared__ short Kls[4 * 2 * 64 * 16];   // [mm][ri][o][b] bf16, 16 KB
  const int t = threadIdx.x;
  const int l = t & 63;
  const int w = t >> 6;
  const int lr = l & 15;
  const int lg = l >> 4;
  const int mg = blockIdx.x;               // 0..272
  int m = mg * 4 + w; if (m > 1088) m = 1088;

  // A fragments from Xp (64B-line coalesced)
  s8v xr[2], xi[2], nxi[2];
#pragma unroll
  for (int ks = 0; ks < 2; ++ks) {
#pragma unroll
    for (int e = 0; e < 8; ++e) {
      unsigned u = Xp[((size_t)m * 64 + ks * 32 + lg * 8 + e) * 16 + lr];
      xr[ks][e] = (short)(u & 0xFFFFu);
      unsigned short hi = (unsigned short)(u >> 16);
      xi[ks][e] = (short)hi;
      nxi[ks][e] = (short)(hi ^ 0x8000u);
    }
  }

  const s8v* Wm = Wfrag + (size_t)m * 16 * 64;   // 16 frags/mode, 64 s8v each
#pragma unroll
  for (int ot = 0; ot < 4; ++ot) {
    s8v rr0 = Wm[((ot * 2 + 0) * 2 + 0) * 64 + l];
    s8v rr1 = Wm[((ot * 2 + 0) * 2 + 1) * 64 + l];
    s8v ri0 = Wm[((ot * 2 + 1) * 2 + 0) * 64 + l];
    s8v ri1 = Wm[((ot * 2 + 1) * 2 + 1) * 64 + l];
    f4v kr = {0.f, 0.f, 0.f, 0.f}, ki = {0.f, 0.f, 0.f, 0.f};
    kr = __builtin_amdgcn_mfma_f32_16x16x32_bf16(xr[0], rr0, kr, 0, 0, 0);
    kr = __builtin_amdgcn_mfma_f32_16x16x32_bf16(xr[1], rr1, kr, 0, 0, 0);
    kr = __builtin_amdgcn_mfma_f32_16x16x32_bf16(nxi[0], ri0, kr, 0, 0, 0);
    kr = __builtin_amdgcn_mfma_f32_16x16x32_bf16(nxi[1], ri1, kr, 0, 0, 0);
    ki = __builtin_amdgcn_mfma_f32_16x16x32_bf16(xr[0], ri0, ki, 0, 0, 0);
    ki = __builtin_amdgcn_mfma_f32_16x16x32_bf16(xr[1], ri1, ki, 0, 0, 0);
    ki = __builtin_amdgcn_mfma_f32_16x16x32_bf16(xi[0], rr0, ki, 0, 0, 0);
    ki = __builtin_amdgcn_mfma_f32_16x16x32_bf16(xi[1], rr1, ki, 0, 0, 0);
    // D: col o = ot*16+lr, rows b = lg*4+r
    *reinterpret_cast<uint2*>(&Kls[((w * 2 + 0) * 64 + ot * 16 + lr) * 16 + lg * 4]) = pack4(kr);
    *reinterpret_cast<uint2*>(&Kls[((w * 2 + 1) * 64 + ot * 16 + lr) * 16 + lg * 4]) = pack4(ki);
  }
  __syncthreads();

  // writeout: per img 8B runs (4 modes), full-line coverage within block
#pragma unroll
  for (int rep = 0; rep < 4; ++rep) {
    int img = rep * 256 + t;
    int b = img >> 6, o = img & 63;
#pragma unroll
    for (int ri = 0; ri < 2; ++ri) {
      unsigned short v[4];
#pragma unroll
      for (int mm = 0; mm < 4; ++mm)
        v[mm] = (unsigned short)Kls[((mm * 2 + ri) * 64 + o) * 16 + b];
      uint2 u;
      u.x = (unsigned)v[0] | ((unsigned)v[1] << 16);
      u.y = (unsigned)v[2] | ((unsigned)v[3] << 16);
      *reinterpret_cast<uint2*>(Kbf + ((size_t)(mg * 1024 + img) * 2 + ri) * 4) = u;
    }
  }
}

// ---------------------------------------------------------------- inverse DFT
__global__ __launch_bounds__(256) void spc_inv_mfma(const short* __restrict__ Kbf,
                                                    const s8v* __restrict__ T3,
                                                    const s8v* __restrict__ T4,
                                                    float* __restrict__ out) {
  __shared__ short Kls2[2 * MPAD];  // per-image K slice (4416 B)
  __shared__ short Vt[128 * 128];   // stacked [T1; -T2] rows i'<96, [m][i'] swizzled
  const int t = threadIdx.x;
  const int l = t & 63;
  const int w = t >> 6;
  const int lr = l & 15;
  const int lg = l >> 4;
  const int img = blockIdx.x;

  {
    const uint2* src = reinterpret_cast<const uint2*>(Kbf);
    uint2* dstl = reinterpret_cast<uint2*>(Kls2);
    for (int g = t; g < 546; g += 256) {          // 273 mg × 2 ri
      int mgi = g >> 1, ri = g & 1;
      dstl[ri * 276 + mgi] = src[((size_t)(mgi * 1024 + img)) * 2 + ri];
    }
  }
  __syncthreads();

  // build Kr/Ki A-fragments: [ri][it<3][ks<2], row i=it*16+lr, k j=ks*32+lg*8+e
  s8v fr[2][3][2];
#pragma unroll
  for (int ri2 = 0; ri2 < 2; ++ri2)
#pragma unroll
    for (int it = 0; it < 3; ++it)
#pragma unroll
      for (int ks = 0; ks < 2; ++ks) {
        const int i = it * 16 + lr;
#pragma unroll
        for (int e = 0; e < 8; ++e) {
          const int j = ks * 32 + lg * 8 + e;
          unsigned short v = (i < 33 && j < 33)
              ? (unsigned short)Kls2[ri2 * MPAD + i * 33 + j] : (unsigned short)0;
          fr[ri2][it][ks][e] = (short)v;
        }
      }

  // stage 1: T1[i][m] = Kr·Cw − Ki·Sw ; T2 = Ki·Cw + Kr·Sw ; store [T1; −T2]
  for (int mm = 0; mm < 2; ++mm) {
    const int mt = w * 2 + mm;
    const int m = mt * 16 + lr;
    s8v cw[2], sw[2], nsw[2];
#pragma unroll
    for (int ks = 0; ks < 2; ++ks) {
      cw[ks] = T3[((0 * 2 + ks) * 8 + mt) * 64 + l];
      sw[ks] = T3[((1 * 2 + ks) * 8 + mt) * 64 + l];
#pragma unroll
      for (int e = 0; e < 8; ++e)
        nsw[ks][e] = (short)(((unsigned short)sw[ks][e]) ^ 0x8000u);
    }
#pragma unroll
    for (int it = 0; it < 3; ++it) {
      f4v t1 = {0.f, 0.f, 0.f, 0.f}, t2 = {0.f, 0.f, 0.f, 0.f};
#pragma unroll
      for (int ks = 0; ks < 2; ++ks) {
        t1 = __builtin_amdgcn_mfma_f32_16x16x32_bf16(fr[0][it][ks], cw[ks],  t1, 0, 0, 0);
        t1 = __builtin_amdgcn_mfma_f32_16x16x32_bf16(fr[1][it][ks], nsw[ks], t1, 0, 0, 0);
        t2 = __builtin_amdgcn_mfma_f32_16x16x32_bf16(fr[1][it][ks], cw[ks],  t2, 0, 0, 0);
        t2 = __builtin_amdgcn_mfma_f32_16x16x32_bf16(fr[0][it][ks], sw[ks],  t2, 0, 0, 0);
      }
      const int base1 = it * 16 + lg * 4;
      const int g1 = (base1 >> 2) ^ ((m & 7) << 2);
      *reinterpret_cast<uint2*>(&Vt[m * 128 + g1 * 4]) = pack4(t1);
      f4v nt2v = {-t2[0], -t2[1], -t2[2], -t2[3]};
      const int g2 = ((48 + base1) >> 2) ^ ((m & 7) << 2);
      *reinterpret_cast<uint2*>(&Vt[m * 128 + g2 * 4]) = pack4(nt2v);
    }
  }
  __syncthreads();

  // stage 2: out[n][m] = sum_{i'<96} A2[n][i'] · Vt[i'][m]
  float* op = out + (size_t)img * (NH * NW);
  for (int nn = 0; nn < 2; ++nn) {
    const int nt = w * 2 + nn;
    s8v a[3];
#pragma unroll
    for (int ks = 0; ks < 3; ++ks) a[ks] = T4[(nt * 3 + ks) * 64 + l];
    for (int mt = 0; mt < 8; ++mt) {
      const int m = mt * 16 + lr;
      f4v acc = {0.f, 0.f, 0.f, 0.f};
#pragma unroll
      for (int ks = 0; ks < 3; ++ks) {
        const int g = (ks * 8 + lg * 2) ^ ((m & 7) << 2);
        s8v bb = *reinterpret_cast<const s8v*>(&Vt[m * 128 + g * 4]);
        acc = __builtin_amdgcn_mfma_f32_16x16x32_bf16(a[ks], bb, acc, 0, 0, 0);
      }
      const int n = nt * 16 + lg * 4;
#pragma unroll
      for (int r = 0; r < 4; ++r) op[(n + r) * NW + m] = acc[r];
    }
  }
}

// ---------------------------------------------------------------- launch
extern "C" void kernel_launch(void* const* d_in, const int* in_sizes, int n_in,
                              void* d_out, int out_size, void* d_ws, size_t ws_size,
                              hipStream_t stream) {
  const float* x  = (const float*)d_in[0];
  const float* wr = (const float*)d_in[1];
  const float* wi = (const float*)d_in[2];
  float* out = (float*)d_out;

  char* ws = (char*)d_ws;
  short* T1 = (short*)(ws);                    // 20480 B
  short* T2 = (short*)(ws + 20480);            // 20480 B
  short* T3 = (short*)(ws + 40960);            // 32768 B
  short* T4 = (short*)(ws + 73728);            // 24576 B  -> 98304
  short* Wfrag = (short*)(ws + 98304);         // 1104*8192*2 = 18,087,936 -> 18,186,240
  unsigned* X2u = (unsigned*)(ws + 18186240);  // 1024*1089*4 = 4,460,544
  short* Kbf = (short*)(ws + 18186240);        // ALIAS X2u (dead after xrepack): 4,472,832
  unsigned* Xp = (unsigned*)(ws + 22659072);   // 4,460,544 -> 27,119,616 total

  hipLaunchKernelGGL(spc_tables, dim3(192), dim3(256), 0, stream, T1, T2, T3, T4);
  hipLaunchKernelGGL(spc_wrepack, dim3(4, 69), dim3(256), 0, stream, wr, wi, Wfrag);
  hipLaunchKernelGGL(spc_fwd_mfma, dim3(NIMG), dim3(256), 0, stream,
                     x, (const s8v*)T1, (const s8v*)T2, X2u);
  hipLaunchKernelGGL(spc_xrepack, dim3(18, 16), dim3(256), 0, stream, X2u, Xp);
  hipLaunchKernelGGL(spc_mix_mfma, dim3(273), dim3(256), 0, stream,
                     Xp, (const s8v*)Wfrag, Kbf);
  hipLaunchKernelGGL(spc_inv_mfma, dim3(NIMG), dim3(256), 0, stream,
                     Kbf, (const s8v*)T3, (const s8v*)T4, out);
}